// Round 22
// baseline (141.259 us; speedup 1.0000x reference)
//
#include <hip/hip_runtime.h>

typedef unsigned int uint;
typedef unsigned short ushort;
using short8 = __attribute__((ext_vector_type(8))) short;   // 8 bf16 (4 VGPRs)
using f32x4  = __attribute__((ext_vector_type(4))) float;

#define NHALF 2048
#define DIM   1024
#define MROWS 4096
#define KMED  8388607u
#define NTRI  528            // 32*33/2 lower-triangle 128x128 blocks

// workspace layout (bytes) — no L2 matrix
#define AH_OFF   0ull                          // 8 MB bf16 hi
#define SQ_OFF   8388608ull                    // 16 KB f32 sq norms (exact)
#define GHT_OFF  (SQ_OFF + 16384ull)           // 65600 B: TOTAL hist bits 29:16 (16384 u32) + low word [16384]
#define GHN_OFF  (GHT_OFF + 65600ull)          // 65600 B: NEG (cross-half) hist + low word
#define CNT_OFF  (GHN_OFF + 65600ull)          // 16 B: cnt[0]=prep-done cnt[1]=flush-done
#define MEMSET_BYTES (65600ull * 2 + 16ull)    // GHT + GHN + CNT contiguous

#define AGLOAD(p)      __hip_atomic_load((p), __ATOMIC_RELAXED, __HIP_MEMORY_SCOPE_AGENT)
#define AGLOAD_ACQ(p)  __hip_atomic_load((p), __ATOMIC_ACQUIRE, __HIP_MEMORY_SCOPE_AGENT)

__device__ __forceinline__ ushort f2bf(float x) {
    uint u = __float_as_uint(x);
    u += 0x7FFFu + ((u >> 16) & 1u);           // RNE
    return (ushort)(u >> 16);
}

// stage chunk cidx (16 rows x 32 cols = 1KB) of [buf][arr]
#define STAGE1(buf, arr, srcp, rb, cidx) do {                                              \
    int _i = (cidx) * 64 + lane;                                                           \
    const ushort* _g = (srcp) + ((size_t)((rb) + (_i >> 2)) * DIM + kk0 + (_i & 3) * 8);   \
    __builtin_amdgcn_global_load_lds(                                                      \
        (const __attribute__((address_space(1))) uint*)_g,                                 \
        (__attribute__((address_space(3))) uint*)(&lds[buf][arr][0][0] + (size_t)(cidx) * 512), \
        16, 0, 0);                                                                         \
} while (0)

// ---------------------------------------------------------------- single fused kernel
__global__ __launch_bounds__(512, 4) void mmd_kernel(const float* __restrict__ src,
                                                     const float* __restrict__ tgt,
                                                     char* __restrict__ wsb,
                                                     float* __restrict__ out) {
    ushort* ah = (ushort*)(wsb + AH_OFF);
    float*  sq = (float*)(wsb + SQ_OFF);
    uint*   ght = (uint*)(wsb + GHT_OFF);
    uint*   ghn = (uint*)(wsb + GHN_OFF);
    uint*   cnt = (uint*)(wsb + CNT_OFF);

    // union: staging [2buf][2arr][128][32] (32 KB) / hist (32 KB)
    __shared__ __align__(16) uint shmem[8192];
    __shared__ uint lowcnt;
    __shared__ float fred[8];
    ushort (*lds)[2][128][32] = (ushort (*)[2][128][32])shmem;

    int t = threadIdx.x;
    int lane = t & 63, wid = t >> 6;         // 8 waves
    int b0 = (int)blockIdx.x;

    // ---- phase A: prep — blocks 0..511 convert 8 rows each (1 row/wave), exact sq
    if (b0 < 512) {
        int row = b0 * 8 + wid;
        const float* p = (row < NHALF) ? src + (size_t)row * DIM
                                       : tgt + (size_t)(row - NHALF) * DIM;
        float s = 0.0f;
#pragma unroll
        for (int c = 0; c < 4; ++c) {
            float4 v = *reinterpret_cast<const float4*>(p + lane * 16 + c * 4);
            s += v.x * v.x + v.y * v.y + v.z * v.z + v.w * v.w;
            ushort4 u4; u4.x = f2bf(v.x); u4.y = f2bf(v.y); u4.z = f2bf(v.z); u4.w = f2bf(v.w);
            *reinterpret_cast<ushort4*>(ah + (size_t)row * DIM + lane * 16 + c * 4) = u4;
        }
        for (int o = 32; o; o >>= 1) s += __shfl_down(s, o);
        if (lane == 0) sq[row] = s;
        __syncthreads();
        if (t == 0) {
            __threadfence();
            atomicAdd(&cnt[0], 1u);
        }
    }

    // ---- phase B: wait for all panels converted (all 528 blocks co-resident: 4/CU x 256)
    if (t == 0) {
        while (AGLOAD_ACQ(&cnt[0]) < 512u) __builtin_amdgcn_s_sleep(2);
    }
    __syncthreads();

    // XCD swizzle (528 = 8*66, bijective) then triangular decode
    int b = b0;
    b = (b & 7) * 66 + (b >> 3);
    int bi = (int)((sqrtf(8.0f * (float)b + 1.0f) - 1.0f) * 0.5f);
    while ((bi + 1) * (bi + 2) / 2 <= b) ++bi;
    while (bi * (bi + 1) / 2 > b) --bi;
    int bj = b - bi * (bi + 1) / 2;          // bj <= bi

    int wm = wid >> 2, wn = wid & 3;         // 2x4 wave grid: 64 rows x 32 cols per wave
    int rowbase = bi * 128, colbase = bj * 128;

    f32x4 acc[4][2] = {};
    int fr = lane & 15, fk = (lane >> 4) * 8;

    {   // prologue: stage k-step 0 into buffer 0 (wave wid stages chunk wid of A and B)
        int kk0 = 0;
        STAGE1(0, 0, ah, rowbase, wid);
        STAGE1(0, 1, ah, colbase, wid);
    }
    __syncthreads();

    int cur = 0;
    for (int kt = 0; kt < 32; ++kt) {
        if (kt < 31) {                        // issue next-tile loads BEFORE compute
            int kk0 = (kt + 1) * 32;
            int nb = cur ^ 1;
            STAGE1(nb, 0, ah, rowbase, wid);
            STAGE1(nb, 1, ah, colbase, wid);
        }
        short8 fa[4], fb[2];
#pragma unroll
        for (int m = 0; m < 4; ++m)
            fa[m] = *reinterpret_cast<const short8*>(&lds[cur][0][wm * 64 + m * 16 + fr][fk]);
#pragma unroll
        for (int n = 0; n < 2; ++n)
            fb[n] = *reinterpret_cast<const short8*>(&lds[cur][1][wn * 32 + n * 16 + fr][fk]);
#pragma unroll
        for (int m = 0; m < 4; ++m)
#pragma unroll
            for (int n = 0; n < 2; ++n)
                acc[m][n] = __builtin_amdgcn_mfma_f32_16x16x32_bf16(fa[m], fb[n], acc[m][n], 0, 0, 0);
        __syncthreads();                      // drains next-tile vmcnt + this tile's readers
        cur ^= 1;
    }

    // ---- phase C: bit30-split hist from registers (sign is BLOCK-uniform)
    uint* h = shmem;                          // 8192 packed words = 32 KB
    for (int i = t; i < 8192; i += 512) h[i] = 0;
    if (t == 0) lowcnt = 0;
    __syncthreads();

    uint w = (bi == bj) ? 1u : 2u;
    int fq = lane >> 4;
#pragma unroll
    for (int m = 0; m < 4; ++m) {
#pragma unroll
        for (int n = 0; n < 2; ++n) {
            int gj = colbase + wn * 32 + n * 16 + fr;
            float sqj = sq[gj];
#pragma unroll
            for (int r = 0; r < 4; ++r) {
                int gi = rowbase + wm * 64 + m * 16 + fq * 4 + r;
                float v = fmaxf(sq[gi] + sqj - 2.0f * acc[m][n][r], 0.0f);
                uint bits = __float_as_uint(v);
                if (bits & 0x40000000u) {
                    uint k14 = (bits >> 16) & 0x3FFFu;
                    atomicAdd(&h[k14 >> 1], (k14 & 1) ? (w << 16) : w);
                } else {
                    atomicAdd(&lowcnt, w);             // rare (diag zeros + tiny tail)
                }
            }
        }
    }
    __syncthreads();

    // ---- phase D: flush. Always -> total; cross-half blocks also -> neg hist.
    bool crosshalf = (bi < 16) != (bj < 16);
    for (int i = t; i < 8192; i += 512) {
        uint wd = h[i];
        if (wd) {
            uint lo = wd & 0xFFFFu, hi2 = wd >> 16;
            if (lo)  { atomicAdd(&ght[2 * i],     lo);  if (crosshalf) atomicAdd(&ghn[2 * i],     lo); }
            if (hi2) { atomicAdd(&ght[2 * i + 1], hi2); if (crosshalf) atomicAdd(&ghn[2 * i + 1], hi2); }
        }
    }
    if (t == 0 && lowcnt) {
        atomicAdd(&ght[16384], lowcnt);
        if (crosshalf) atomicAdd(&ghn[16384], lowcnt);
    }

    // ---- phase E: last-flusher computes median AND loss from the histograms
    __syncthreads();
    if (t == 0) {
        __threadfence();
        h[0] = (atomicAdd(&cnt[1], 1u) == gridDim.x - 1) ? 1u : 0u;
    }
    __syncthreads();
    bool last = h[0] != 0;
    __syncthreads();
    if (!last) return;

    uint* part = h + 16;       // 512
    uint* loc  = h + 544;      // 2
    uint* lin  = h + 560;      // 32
    uint s = 0;
    for (int i = 0; i < 32; ++i) s += AGLOAD(&ght[t * 32 + i]);   // 512 thr x 32 bins
    part[t] = s;
    __syncthreads();
    if (t == 0) {
        uint k = KMED - AGLOAD(&ght[16384]);   // below-2.0 values rank below everything
        uint cum = 0; int seg = 0;
        for (; seg < 512; ++seg) { uint c = part[seg]; if (cum + c > k) break; cum += c; }
        loc[0] = (uint)seg; loc[1] = k - cum;
    }
    __syncthreads();
    int seg = (int)loc[0];
    if (t < 32) lin[t] = AGLOAD(&ght[seg * 32 + t]);
    __syncthreads();
    if (t == 0) {
        uint k = loc[1], cum = 0; int bb = 0;
        for (; bb < 32; ++bb) { uint c = lin[bb]; if (cum + c > k) break; cum += c; }
        // median resolved to bits >= 16; bin midpoint (err <= 8 abs @ ~2048)
        uint mbits = 0x40000000u | ((uint)(seg * 32 + bb) << 16) | 0x8000u;
        float median = __uint_as_float(mbits);
        float logn = logf(2048.0f + 1e-8f);
        float bw = sqrtf(0.5f * median / logn);
        out[1] = bw;                               // bandwidth
        ((float*)loc)[1] = logn / median;          // itb -> LDS for all threads
    }
    __syncthreads();
    float itb = ((float*)loc)[1];

    // loss = sum over bins of (total - 2*neg) * exp(-mid * itb), + low-count at exp(0)=1
    float local = 0.0f;
    for (int i = 0; i < 32; ++i) {
        int bidx = t * 32 + i;
        int tot = (int)AGLOAD(&ght[bidx]);
        int neg = (int)AGLOAD(&ghn[bidx]);
        int sgn = tot - 2 * neg;
        if (sgn) {
            float mid = __uint_as_float(0x40000000u | ((uint)bidx << 16) | 0x8000u);
            local += (float)sgn * __expf(-mid * itb);
        }
    }
    if (t == 0)
        local += (float)((int)AGLOAD(&ght[16384]) - 2 * (int)AGLOAD(&ghn[16384]));  // exp(0)=1
    for (int o = 32; o; o >>= 1) local += __shfl_down(local, o);
    if ((t & 63) == 0) fred[t >> 6] = local;
    __syncthreads();
    if (t == 0) {
        float bs = fred[0] + fred[1] + fred[2] + fred[3]
                 + fred[4] + fred[5] + fred[6] + fred[7];
        out[0] = bs / 4194304.0f;              // mean over N*N, N=2048
    }
}

// ---------------------------------------------------------------- launch (1 memset + 1 kernel)
extern "C" void kernel_launch(void* const* d_in, const int* in_sizes, int n_in,
                              void* d_out, int out_size, void* d_ws, size_t ws_size,
                              hipStream_t stream) {
    const float* src = (const float*)d_in[0];
    const float* tgt = (const float*)d_in[1];
    float* out = (float*)d_out;
    char* ws = (char*)d_ws;

    hipMemsetAsync(ws + GHT_OFF, 0, MEMSET_BYTES, stream);   // zero hists + counters
    mmd_kernel<<<NTRI, 512, 0, stream>>>(src, tgt, ws, out);
}

// Round 23
// 84.753 us; speedup vs baseline: 1.6667x; 1.6667x over previous
//
#include <hip/hip_runtime.h>

typedef unsigned int uint;
typedef unsigned short ushort;
using short8 = __attribute__((ext_vector_type(8))) short;   // 8 bf16 (4 VGPRs)
using f32x4  = __attribute__((ext_vector_type(4))) float;

#define NHALF 2048
#define DIM   1024
#define MROWS 4096
#define KMED  8388607u
#define NTRI  528            // 32*33/2 lower-triangle 128x128 blocks

// workspace layout (bytes) — no L2 matrix
#define AH_OFF   0ull                          // 8 MB bf16 hi
#define SQ_OFF   8388608ull                    // 16 KB f32 sq norms (exact)
#define GHT_OFF  (SQ_OFF + 16384ull)           // 65600 B: TOTAL hist bits 29:16 (16384 u32) + low word [16384]
#define GHN_OFF  (GHT_OFF + 65600ull)          // 65600 B: NEG (cross-half) hist + low word
#define CNT_OFF  (GHN_OFF + 65600ull)          // 16 B: cnt[0]=flush-done
#define ZERO_WORDS 32804                       // (65600*2 + 16)/4 from GHT_OFF

#define AGLOAD(p) __hip_atomic_load((p), __ATOMIC_RELAXED, __HIP_MEMORY_SCOPE_AGENT)

__device__ __forceinline__ ushort f2bf(float x) {
    uint u = __float_as_uint(x);
    u += 0x7FFFu + ((u >> 16) & 1u);           // RNE
    return (ushort)(u >> 16);
}

// ---------------------------------------------------------------- dispatch 1: zero scratch + f32->bf16 + sqnorm
__global__ __launch_bounds__(256) void convert_kernel(const float* __restrict__ src,
                                                      const float* __restrict__ tgt,
                                                      char* __restrict__ wsb) {
    ushort* ah = (ushort*)(wsb + AH_OFF);
    float*  sq = (float*)(wsb + SQ_OFF);
    uint*   z  = (uint*)(wsb + GHT_OFF);
    int t = threadIdx.x, row = blockIdx.x;
    int g = row * 256 + t;
    if (g < ZERO_WORDS) z[g] = 0;              // zeros both hists + counters
    const float* p = (row < NHALF) ? src + (size_t)row * DIM
                                   : tgt + (size_t)(row - NHALF) * DIM;
    float4 v = reinterpret_cast<const float4*>(p)[t];
    float xs[4] = {v.x, v.y, v.z, v.w};
    ushort hh[4];
    float s = 0.0f;
#pragma unroll
    for (int e = 0; e < 4; ++e) { float x = xs[e]; s += x * x; hh[e] = f2bf(x); }
    ushort4 h4; h4.x = hh[0]; h4.y = hh[1]; h4.z = hh[2]; h4.w = hh[3];
    reinterpret_cast<ushort4*>(ah + (size_t)row * DIM)[t] = h4;
    for (int o = 32; o; o >>= 1) s += __shfl_down(s, o);
    __shared__ float red[4];
    if ((t & 63) == 0) red[t >> 6] = s;
    __syncthreads();
    if (t == 0) sq[row] = red[0] + red[1] + red[2] + red[3];
}

// ---------------------------------------------------------------- dispatch 2: GEMM + hist + last-block {median, hist-loss}
#define STAGE1(buf, arr, srcp, rb, cidx) do {                                              \
    int _i = (cidx) * 64 + lane;                                                           \
    const ushort* _g = (srcp) + ((size_t)((rb) + (_i >> 2)) * DIM + kk0 + (_i & 3) * 8);   \
    __builtin_amdgcn_global_load_lds(                                                      \
        (const __attribute__((address_space(1))) uint*)_g,                                 \
        (__attribute__((address_space(3))) uint*)(&lds[buf][arr][0][0] + (size_t)(cidx) * 512), \
        16, 0, 0);                                                                         \
} while (0)

__global__ __launch_bounds__(512, 4) void gemm_kernel(char* __restrict__ wsb,
                                                      float* __restrict__ out) {
    const ushort* ah = (const ushort*)(wsb + AH_OFF);
    const float*  sq = (const float*)(wsb + SQ_OFF);
    uint*  ght = (uint*)(wsb + GHT_OFF);
    uint*  ghn = (uint*)(wsb + GHN_OFF);
    uint*  cnt = (uint*)(wsb + CNT_OFF);

    // union: staging [2buf][2arr][128][32] (32 KB) / hist (32 KB)
    __shared__ __align__(16) uint shmem[8192];
    __shared__ uint lowcnt;
    __shared__ float fred[8];
    ushort (*lds)[2][128][32] = (ushort (*)[2][128][32])shmem;

    // XCD swizzle (528 = 8*66, bijective) then triangular decode
    int b = (int)blockIdx.x;
    b = (b & 7) * 66 + (b >> 3);
    int bi = (int)((sqrtf(8.0f * (float)b + 1.0f) - 1.0f) * 0.5f);
    while ((bi + 1) * (bi + 2) / 2 <= b) ++bi;
    while (bi * (bi + 1) / 2 > b) --bi;
    int bj = b - bi * (bi + 1) / 2;          // bj <= bi

    int t = threadIdx.x;
    int lane = t & 63, wid = t >> 6;         // 8 waves
    int wm = wid >> 2, wn = wid & 3;         // 2x4 wave grid: 64 rows x 32 cols per wave
    int rowbase = bi * 128, colbase = bj * 128;

    f32x4 acc[4][2] = {};
    int fr = lane & 15, fk = (lane >> 4) * 8;

    {   // prologue: stage k-step 0 into buffer 0 (wave wid stages chunk wid of A and B)
        int kk0 = 0;
        STAGE1(0, 0, ah, rowbase, wid);
        STAGE1(0, 1, ah, colbase, wid);
    }
    __syncthreads();

    int cur = 0;
    for (int kt = 0; kt < 32; ++kt) {
        if (kt < 31) {                        // issue next-tile loads BEFORE compute
            int kk0 = (kt + 1) * 32;
            int nb = cur ^ 1;
            STAGE1(nb, 0, ah, rowbase, wid);
            STAGE1(nb, 1, ah, colbase, wid);
        }
        short8 fa[4], fb[2];
#pragma unroll
        for (int m = 0; m < 4; ++m)
            fa[m] = *reinterpret_cast<const short8*>(&lds[cur][0][wm * 64 + m * 16 + fr][fk]);
#pragma unroll
        for (int n = 0; n < 2; ++n)
            fb[n] = *reinterpret_cast<const short8*>(&lds[cur][1][wn * 32 + n * 16 + fr][fk]);
#pragma unroll
        for (int m = 0; m < 4; ++m)
#pragma unroll
            for (int n = 0; n < 2; ++n)
                acc[m][n] = __builtin_amdgcn_mfma_f32_16x16x32_bf16(fa[m], fb[n], acc[m][n], 0, 0, 0);
        __syncthreads();                      // drains next-tile vmcnt + this tile's readers
        cur ^= 1;
    }

    // ---- phase 2: bit30-split hist from registers (sign is BLOCK-uniform; no per-elem sign)
    uint* h = shmem;                          // 8192 packed words = 32 KB
    for (int i = t; i < 8192; i += 512) h[i] = 0;
    if (t == 0) lowcnt = 0;
    __syncthreads();

    uint w = (bi == bj) ? 1u : 2u;
    int fq = lane >> 4;
#pragma unroll
    for (int m = 0; m < 4; ++m) {
#pragma unroll
        for (int n = 0; n < 2; ++n) {
            int gj = colbase + wn * 32 + n * 16 + fr;
            float sqj = sq[gj];
#pragma unroll
            for (int r = 0; r < 4; ++r) {
                int gi = rowbase + wm * 64 + m * 16 + fq * 4 + r;
                float v = fmaxf(sq[gi] + sqj - 2.0f * acc[m][n][r], 0.0f);
                uint bits = __float_as_uint(v);
                if (bits & 0x40000000u) {
                    uint k14 = (bits >> 16) & 0x3FFFu;
                    atomicAdd(&h[k14 >> 1], (k14 & 1) ? (w << 16) : w);
                } else {
                    atomicAdd(&lowcnt, w);             // rare (diag zeros + tiny tail)
                }
            }
        }
    }
    __syncthreads();

    // ---- phase 3: flush. Always -> total; cross-half blocks also -> neg hist.
    bool crosshalf = (bi < 16) != (bj < 16);
    for (int i = t; i < 8192; i += 512) {
        uint wd = h[i];
        if (wd) {
            uint lo = wd & 0xFFFFu, hi2 = wd >> 16;
            if (lo)  { atomicAdd(&ght[2 * i],     lo);  if (crosshalf) atomicAdd(&ghn[2 * i],     lo); }
            if (hi2) { atomicAdd(&ght[2 * i + 1], hi2); if (crosshalf) atomicAdd(&ghn[2 * i + 1], hi2); }
        }
    }
    if (t == 0 && lowcnt) {
        atomicAdd(&ght[16384], lowcnt);
        if (crosshalf) atomicAdd(&ghn[16384], lowcnt);
    }

    // ---- phase 4: last-flusher computes median AND loss from the histograms
    __syncthreads();
    if (t == 0) {
        __threadfence();
        h[0] = (atomicAdd(&cnt[0], 1u) == gridDim.x - 1) ? 1u : 0u;
    }
    __syncthreads();
    bool last = h[0] != 0;
    __syncthreads();
    if (!last) return;

    uint* part = h + 16;       // 512
    uint* loc  = h + 544;      // 2
    uint* lin  = h + 560;      // 32
    uint s = 0;
    for (int i = 0; i < 32; ++i) s += AGLOAD(&ght[t * 32 + i]);   // 512 thr x 32 bins
    part[t] = s;
    __syncthreads();
    if (t == 0) {
        uint k = KMED - AGLOAD(&ght[16384]);   // below-2.0 values rank below everything
        uint cum = 0; int seg = 0;
        for (; seg < 512; ++seg) { uint c = part[seg]; if (cum + c > k) break; cum += c; }
        loc[0] = (uint)seg; loc[1] = k - cum;
    }
    __syncthreads();
    int seg = (int)loc[0];
    if (t < 32) lin[t] = AGLOAD(&ght[seg * 32 + t]);
    __syncthreads();
    if (t == 0) {
        uint k = loc[1], cum = 0; int bb = 0;
        for (; bb < 32; ++bb) { uint c = lin[bb]; if (cum + c > k) break; cum += c; }
        // median resolved to bits >= 16; bin midpoint (err <= 8 abs @ ~2048)
        uint mbits = 0x40000000u | ((uint)(seg * 32 + bb) << 16) | 0x8000u;
        float median = __uint_as_float(mbits);
        float logn = logf(2048.0f + 1e-8f);
        float bw = sqrtf(0.5f * median / logn);
        out[1] = bw;                               // bandwidth
        ((float*)loc)[1] = logn / median;          // itb -> LDS for all threads (loc[1] free now)
    }
    __syncthreads();
    float itb = ((float*)loc)[1];

    // loss = sum over bins of (total - 2*neg) * exp(-mid * itb), + low-count at exp(0)=1
    float local = 0.0f;
    for (int i = 0; i < 32; ++i) {
        int bidx = t * 32 + i;
        int tot = (int)AGLOAD(&ght[bidx]);
        int neg = (int)AGLOAD(&ghn[bidx]);
        int sgn = tot - 2 * neg;
        if (sgn) {
            float mid = __uint_as_float(0x40000000u | ((uint)bidx << 16) | 0x8000u);
            local += (float)sgn * __expf(-mid * itb);
        }
    }
    if (t == 0)
        local += (float)((int)AGLOAD(&ght[16384]) - 2 * (int)AGLOAD(&ghn[16384]));  // exp(0)=1
    for (int o = 32; o; o >>= 1) local += __shfl_down(local, o);
    if ((t & 63) == 0) fred[t >> 6] = local;
    __syncthreads();
    if (t == 0) {
        float bs = fred[0] + fred[1] + fred[2] + fred[3]
                 + fred[4] + fred[5] + fred[6] + fred[7];
        out[0] = bs / 4194304.0f;              // mean over N*N, N=2048
    }
}

// ---------------------------------------------------------------- launch (2 dispatches)
extern "C" void kernel_launch(void* const* d_in, const int* in_sizes, int n_in,
                              void* d_out, int out_size, void* d_ws, size_t ws_size,
                              hipStream_t stream) {
    const float* src = (const float*)d_in[0];
    const float* tgt = (const float*)d_in[1];
    float* out = (float*)d_out;
    char* ws = (char*)d_ws;

    convert_kernel<<<MROWS, 256, 0, stream>>>(src, tgt, ws);
    gemm_kernel<<<NTRI, 512, 0, stream>>>(ws, out);
}